// Round 13
// baseline (547.327 us; speedup 1.0000x reference)
//
#include <hip/hip_runtime.h>

#define DIMF 128
#define CAP 128   // max edges per node bucket (deg ~ Poisson(16), max ~45 over 100K nodes)

typedef __bf16 bf16x8 __attribute__((ext_vector_type(8)));
typedef float f32x4 __attribute__((ext_vector_type(4)));

__device__ __forceinline__ unsigned short f2bf(float f) {
    union { float f; unsigned u; } v; v.f = f;
    unsigned r = v.u + 0x7FFFu + ((v.u >> 16) & 1u);
    return (unsigned short)(r >> 16);
}
__device__ __forceinline__ float bf2f(unsigned short h) {
    union { unsigned u; float f; } v; v.u = ((unsigned)h) << 16; return v.f;
}

// ---------------- fused: zero cnt+st, convert W0 -> bf16 ----------------
__global__ __launch_bounds__(256) void k_zero_wconv(int* __restrict__ zbase, int zints,
                                                    const float* __restrict__ W, unsigned short* __restrict__ Wb,
                                                    int n4) {
    int idx = blockIdx.x * 256 + threadIdx.x;
    int z0 = idx * 2;
    if (z0 + 1 < zints) {
        *reinterpret_cast<int2*>(zbase + z0) = int2{0, 0};
    } else if (z0 < zints) {
        zbase[z0] = 0;
    }
    if (idx < n4) {
        float4 v = *reinterpret_cast<const float4*>(W + (size_t)idx * 4);
        ushort4 o = { f2bf(v.x), f2bf(v.y), f2bf(v.z), f2bf(v.w) };
        *reinterpret_cast<ushort4*>(Wb + (size_t)idx * 4) = o;
    }
}

// ---------------- single-pass bucketed edge binning ----------------
__global__ __launch_bounds__(256) void k_fillb(const int* __restrict__ src, int* __restrict__ cnt,
                                               int* __restrict__ order, int E) {
    int e = blockIdx.x * 256 + threadIdx.x;
    if (e < E) {
        int s = src[e];
        int p = atomicAdd(&cnt[s], 1);
        if (p < CAP) order[(size_t)s * CAP + p] = e;
    }
}

// ---------------- gather-mean: one wave per node, half-wave row split (R12 proven) ----------------
__global__ __launch_bounds__(256) void k_gather(const float* __restrict__ ea, const int* __restrict__ order,
                                                const int* __restrict__ cnt,
                                                unsigned short* __restrict__ ve, int n) {
    int node = blockIdx.x * 4 + (threadIdx.x >> 6);
    if (node >= n) return;
    int lane = threadIdx.x & 63;
    int half = lane >> 5;
    int l32 = lane & 31;
    int c = cnt[node];
    if (c > CAP) c = CAP;
    size_t base = (size_t)node * CAP;

    int id0 = (lane < c) ? order[base + lane] : 0;
    int id1 = (c > 64 && lane < c - 64) ? order[base + 64 + lane] : 0;

    int m  = (c > half) ? ((c - half + 1) >> 1) : 0;  // valid rows for this half
    int mu = (c + 1) >> 1;                             // uniform trip count

#define EID(t) ({ int j_ = half + 2 * (t); \
                  (j_ < 64) ? __shfl(id0, j_, 64) : __shfl(id1, j_ - 64, 64); })
#define LDR(eid) __builtin_nontemporal_load(reinterpret_cast<const f32x4*>(ea + (size_t)(eid) * DIMF) + l32)

    f32x4 s = {0.f, 0.f, 0.f, 0.f};
    f32x4 cur[4], nxt[4];
    int tb = mu >> 2;
    if (tb > 0) {
#pragma unroll
        for (int k = 0; k < 4; ++k) cur[k] = LDR(EID(k));
        for (int b = 1; b < tb; ++b) {
#pragma unroll
            for (int k = 0; k < 4; ++k) nxt[k] = LDR(EID(b * 4 + k));
#pragma unroll
            for (int k = 0; k < 4; ++k) {
                int t = (b - 1) * 4 + k;
                if (t < m) s += cur[k];
                cur[k] = nxt[k];
            }
        }
#pragma unroll
        for (int k = 0; k < 4; ++k) {
            int t = (tb - 1) * 4 + k;
            if (t < m) s += cur[k];
        }
    }
    for (int t = tb * 4; t < mu; ++t) {
        f32x4 v = LDR(EID(t));
        if (t < m) s += v;
    }
#undef EID
#undef LDR

    s[0] += __shfl_xor(s[0], 32, 64);
    s[1] += __shfl_xor(s[1], 32, 64);
    s[2] += __shfl_xor(s[2], 32, 64);
    s[3] += __shfl_xor(s[3], 32, 64);

    if (lane < 32) {
        float inv = 1.0f / (float)(c > 1 ? c : 1);
        ushort4 o = { f2bf(s[0] * inv), f2bf(s[1] * inv), f2bf(s[2] * inv), f2bf(s[3] * inv) };
        *reinterpret_cast<ushort4*>(ve + (size_t)node * DIMF + l32 * 4) = o;
    }
}

// ---------------- parallel BN fold: Wb = bf16(W*diag(sS)), bb = b + W@sT ----------------
// grid 128 (one output row/block), block 128
__global__ __launch_bounds__(128) void k_fold(const float* __restrict__ st, const float* __restrict__ g,
                                              const float* __restrict__ bt, const float* __restrict__ Wn,
                                              const float* __restrict__ bn, unsigned short* __restrict__ Wb,
                                              float* __restrict__ bb, int rows) {
    int r = blockIdx.x;
    int i = threadIdx.x;
    float invn = 1.0f / (float)rows;
    float mu = st[i] * invn;
    float var = st[DIMF + i] * invn - mu * mu;
    var = var > 0.f ? var : 0.f;
    float sc = rsqrtf(var + 1e-5f) * g[i];
    float t = bt[i] - mu * sc;
    float w = Wn[(size_t)r * DIMF + i];
    Wb[(size_t)r * DIMF + i] = f2bf(w * sc);
    float p = w * t;
#pragma unroll
    for (int m = 32; m > 0; m >>= 1) p += __shfl_xor(p, m, 64);
    __shared__ float red[2];
    if ((i & 63) == 0) red[i >> 6] = p;
    __syncthreads();
    if (i == 0) bb[r] = bn[r] + red[0] + red[1];
}

#define BM 128

// ---------------- GEMM layer 0: A staged in LDS; B fragments straight from L2-hot global ----------------
__global__ __launch_bounds__(512) void k_gemm0(const float* __restrict__ x,
                                               const unsigned short* __restrict__ ve,
                                               const float* __restrict__ u,
                                               const int* __restrict__ batch,
                                               const unsigned short* __restrict__ W,   // [128][384] bf16
                                               const float* __restrict__ bias,
                                               unsigned short* __restrict__ H,
                                               float* __restrict__ st, int rows) {
    __shared__ __align__(16) unsigned short lA[BM][136];
    __shared__ float sm[DIMF], sq[DIMF];
    __shared__ int sbatch[BM];
    int tid = threadIdx.x;
    int row0 = blockIdx.x * BM;
    if (tid < DIMF) { sm[tid] = 0.f; sq[tid] = 0.f; }
    if (tid < BM) {
        int gr = row0 + tid;
        sbatch[tid] = (gr < rows) ? batch[gr] : 0;
    }
    __syncthreads();  // sbatch ready before chunk-2 staging reads it

    int lane = tid & 63, wave = tid >> 6;
    int wm = wave >> 1, wn = wave & 1;
    int l15 = lane & 15, l4 = lane >> 4;
    f32x4 acc[2][4] = {};

    int fr = tid >> 5, fc = (tid & 31) * 4;
    int hr = tid >> 4, hc = (tid & 15) * 8;
    const unsigned short* wp = W + (size_t)(wn * 64 + l15) * 384 + l4 * 8;

#pragma unroll
    for (int chunk = 0; chunk < 3; ++chunk) {
        if (chunk == 0) {
#pragma unroll
            for (int i = 0; i < 8; ++i) {
                int r = fr + i * 16;
                int gr = row0 + r;
                float4 v = (gr < rows) ? *reinterpret_cast<const float4*>(x + (size_t)gr * DIMF + fc)
                                       : float4{0.f, 0.f, 0.f, 0.f};
                ushort4 o2 = { f2bf(v.x), f2bf(v.y), f2bf(v.z), f2bf(v.w) };
                *reinterpret_cast<ushort4*>(&lA[r][fc]) = o2;
            }
        } else if (chunk == 1) {
#pragma unroll
            for (int i = 0; i < 4; ++i) {
                int r = hr + i * 32;
                int gr = row0 + r;
                uint4 v = (gr < rows) ? *reinterpret_cast<const uint4*>(ve + (size_t)gr * DIMF + hc)
                                      : uint4{0u, 0u, 0u, 0u};
                *reinterpret_cast<uint4*>(&lA[r][hc]) = v;
            }
        } else {
#pragma unroll
            for (int i = 0; i < 8; ++i) {
                int r = fr + i * 16;
                int gr = row0 + r;
                int b = sbatch[r];
                float4 v = (gr < rows) ? *reinterpret_cast<const float4*>(u + (size_t)b * DIMF + fc)
                                       : float4{0.f, 0.f, 0.f, 0.f};
                ushort4 o2 = { f2bf(v.x), f2bf(v.y), f2bf(v.z), f2bf(v.w) };
                *reinterpret_cast<ushort4*>(&lA[r][fc]) = o2;
            }
        }
        __syncthreads();
#pragma unroll
        for (int ks = 0; ks < 4; ++ks) {
            bf16x8 af[2], bfr[4];
#pragma unroll
            for (int ni = 0; ni < 4; ++ni)
                bfr[ni] = *reinterpret_cast<const bf16x8*>(wp + (size_t)ni * 16 * 384 + chunk * 128 + ks * 32);
#pragma unroll
            for (int mi = 0; mi < 2; ++mi)
                af[mi] = *reinterpret_cast<const bf16x8*>(&lA[wm * 32 + mi * 16 + l15][ks * 32 + l4 * 8]);
#pragma unroll
            for (int mi = 0; mi < 2; ++mi)
#pragma unroll
                for (int ni = 0; ni < 4; ++ni)
                    acc[mi][ni] = __builtin_amdgcn_mfma_f32_16x16x32_bf16(af[mi], bfr[ni], acc[mi][ni], 0, 0, 0);
        }
        __syncthreads();
    }

#pragma unroll
    for (int mi = 0; mi < 2; ++mi)
#pragma unroll
        for (int ni = 0; ni < 4; ++ni) {
            int c = wn * 64 + ni * 16 + l15;
            float s = 0.f, q = 0.f;
#pragma unroll
            for (int i = 0; i < 4; ++i) {
                int r = row0 + wm * 32 + mi * 16 + l4 * 4 + i;
                if (r < rows) {
                    float z = acc[mi][ni][i] + bias[c];
                    z = fmaxf(z, 0.f);
                    H[(size_t)r * DIMF + c] = f2bf(z);
                    s += z; q += z * z;
                }
            }
            atomicAdd(&sm[c], s);
            atomicAdd(&sq[c], q);
        }
    __syncthreads();
    if (tid < DIMF) { atomicAdd(&st[tid], sm[tid]); atomicAdd(&st[DIMF + tid], sq[tid]); }
}

// ---------------- GEMM layers 1,2: A in LDS, pre-folded B from global, bias from bb ----------------
__global__ __launch_bounds__(512) void k_gemmN(const unsigned short* __restrict__ A,
                                               const unsigned short* __restrict__ Wb,  // [128][128] bf16 pre-scaled
                                               const float* __restrict__ bb,           // folded bias
                                               unsigned short* __restrict__ H,
                                               float* __restrict__ st, int rows) {
    const int K = 128;
    __shared__ __align__(16) unsigned short lA[BM][136];
    __shared__ float sm[DIMF], sq[DIMF];
    int tid = threadIdx.x;
    int row0 = blockIdx.x * BM;
    if (tid < DIMF) { sm[tid] = 0.f; sq[tid] = 0.f; }

    int hr = tid >> 4, hc = (tid & 15) * 8;
#pragma unroll
    for (int i = 0; i < 4; ++i) {
        int r = hr + i * 32;
        int gr = row0 + r;
        uint4 v = (gr < rows) ? *reinterpret_cast<const uint4*>(A + (size_t)gr * K + hc)
                              : uint4{0u, 0u, 0u, 0u};
        *reinterpret_cast<uint4*>(&lA[r][hc]) = v;
    }
    __syncthreads();

    int lane = tid & 63, wave = tid >> 6;
    int wm = wave >> 1, wn = wave & 1;
    int l15 = lane & 15, l4 = lane >> 4;
    f32x4 acc[2][4] = {};
    const unsigned short* wp = Wb + (size_t)(wn * 64 + l15) * K + l4 * 8;

#pragma unroll
    for (int ks = 0; ks < 4; ++ks) {
        bf16x8 af[2], bfr[4];
#pragma unroll
        for (int ni = 0; ni < 4; ++ni)
            bfr[ni] = *reinterpret_cast<const bf16x8*>(wp + (size_t)ni * 16 * K + ks * 32);
#pragma unroll
        for (int mi = 0; mi < 2; ++mi)
            af[mi] = *reinterpret_cast<const bf16x8*>(&lA[wm * 32 + mi * 16 + l15][ks * 32 + l4 * 8]);
#pragma unroll
        for (int mi = 0; mi < 2; ++mi)
#pragma unroll
            for (int ni = 0; ni < 4; ++ni)
                acc[mi][ni] = __builtin_amdgcn_mfma_f32_16x16x32_bf16(af[mi], bfr[ni], acc[mi][ni], 0, 0, 0);
    }

#pragma unroll
    for (int mi = 0; mi < 2; ++mi)
#pragma unroll
        for (int ni = 0; ni < 4; ++ni) {
            int c = wn * 64 + ni * 16 + l15;
            float s = 0.f, q = 0.f;
#pragma unroll
            for (int i = 0; i < 4; ++i) {
                int r = row0 + wm * 32 + mi * 16 + l4 * 4 + i;
                if (r < rows) {
                    float z = acc[mi][ni][i] + bb[c];
                    z = fmaxf(z, 0.f);
                    H[(size_t)r * DIMF + c] = f2bf(z);
                    s += z; q += z * z;
                }
            }
            atomicAdd(&sm[c], s);
            atomicAdd(&sq[c], q);
        }
    __syncthreads();
    if (tid < DIMF) { atomicAdd(&st[tid], sm[tid]); atomicAdd(&st[DIMF + tid], sq[tid]); }
}

// final: out = h2 * s + t, BN params computed inline from st
__global__ __launch_bounds__(256) void k_final(const unsigned short* __restrict__ H, const float* __restrict__ st,
                                               const float* __restrict__ g, const float* __restrict__ bt,
                                               float* __restrict__ out, int n) {
    int idx = blockIdx.x * 256 + threadIdx.x;
    if (idx >= n * 32) return;
    int r = idx >> 5, q = (idx & 31) * 4;
    float invn = 1.0f / (float)n;
    ushort4 h = *reinterpret_cast<const ushort4*>(H + (size_t)r * DIMF + q);
    float hv[4] = { bf2f(h.x), bf2f(h.y), bf2f(h.z), bf2f(h.w) };
    float ov[4];
#pragma unroll
    for (int k = 0; k < 4; ++k) {
        int c = q + k;
        float mu = st[c] * invn;
        float var = st[DIMF + c] * invn - mu * mu;
        var = var > 0.f ? var : 0.f;
        float sc = rsqrtf(var + 1e-5f) * g[c];
        ov[k] = hv[k] * sc + (bt[c] - mu * sc);
    }
    float4 o = { ov[0], ov[1], ov[2], ov[3] };
    *reinterpret_cast<float4*>(out + (size_t)r * DIMF + q) = o;
}

extern "C" void kernel_launch(void* const* d_in, const int* in_sizes, int n_in,
                              void* d_out, int out_size, void* d_ws, size_t ws_size,
                              hipStream_t stream) {
    const float* x   = (const float*)d_in[0];
    const float* ea  = (const float*)d_in[1];
    const float* u   = (const float*)d_in[2];
    const int* eidx  = (const int*)d_in[3];
    const int* batch = (const int*)d_in[4];
    const float* W0  = (const float*)d_in[5];
    const float* b0  = (const float*)d_in[6];
    const float* W1  = (const float*)d_in[7];
    const float* b1  = (const float*)d_in[8];
    const float* W2  = (const float*)d_in[9];
    const float* b2  = (const float*)d_in[10];
    const float* g0  = (const float*)d_in[11];
    const float* bt0 = (const float*)d_in[12];
    const float* g1  = (const float*)d_in[13];
    const float* bt1 = (const float*)d_in[14];
    const float* g2  = (const float*)d_in[15];
    const float* bt2 = (const float*)d_in[16];

    int N = in_sizes[0] / DIMF;
    int E = in_sizes[1] / DIMF;
    const int* src = eidx;  // row 0 of edge_index

    char* base = (char*)d_ws;
    size_t o = 0;
    auto alloc = [&](size_t sz) { size_t p = o; o = (o + sz + 255) & ~(size_t)255; return p; };
    size_t off_cnt   = alloc((size_t)N * 4);          // zeroed by k_zero_wconv
    size_t off_st    = alloc(3 * 256 * 4);            // zeroed (contiguous with cnt)
    size_t off_order = alloc((size_t)N * CAP * 4);
    size_t off_W0b   = alloc((size_t)DIMF * 384 * 2);
    size_t off_W1b   = alloc((size_t)DIMF * DIMF * 2);
    size_t off_W2b   = alloc((size_t)DIMF * DIMF * 2);
    size_t off_b1f   = alloc(DIMF * 4);
    size_t off_b2f   = alloc(DIMF * 4);
    size_t off_ve    = alloc((size_t)N * DIMF * 2);
    size_t off_h0    = alloc((size_t)N * DIMF * 2);
    size_t off_h1    = alloc((size_t)N * DIMF * 2);
    size_t off_h2    = alloc((size_t)N * DIMF * 2);

    int* cnt        = (int*)(base + off_cnt);
    float* st       = (float*)(base + off_st);
    int* order      = (int*)(base + off_order);
    unsigned short* W0b = (unsigned short*)(base + off_W0b);
    unsigned short* W1b = (unsigned short*)(base + off_W1b);
    unsigned short* W2b = (unsigned short*)(base + off_W2b);
    float* b1f      = (float*)(base + off_b1f);
    float* b2f      = (float*)(base + off_b2f);
    unsigned short* ve  = (unsigned short*)(base + off_ve);
    unsigned short* h0  = (unsigned short*)(base + off_h0);
    unsigned short* h1  = (unsigned short*)(base + off_h1);
    unsigned short* h2  = (unsigned short*)(base + off_h2);
    float* outp = (float*)d_out;

    int zints = (int)((off_st + 3 * 256 * 4) / 4);
    int EB = (E + 255) / 256;
    int NQ = (N * 32 + 255) / 256;
    int GB = (N + BM - 1) / BM;
    int GG = (N + 3) / 4;

    k_zero_wconv<<<256, 256, 0, stream>>>((int*)base, zints, W0, W0b, DIMF * 384 / 4);
    k_fillb<<<EB, 256, 0, stream>>>(src, cnt, order, E);
    k_gather<<<GG, 256, 0, stream>>>(ea, order, cnt, ve, N);

    // layer 0 (stats fused)
    k_gemm0<<<GB, 512, 0, stream>>>(x, ve, u, batch, W0b, b0, h0, st, N);
    // fold BN0 into W1 (parallel, tiny)
    k_fold<<<DIMF, 128, 0, stream>>>(st, g0, bt0, W1, b1, W1b, b1f, N);
    // layer 1
    k_gemmN<<<GB, 512, 0, stream>>>(h0, W1b, b1f, h1, st + 256, N);
    // fold BN1 into W2
    k_fold<<<DIMF, 128, 0, stream>>>(st + 256, g1, bt1, W2, b2, W2b, b2f, N);
    // layer 2
    k_gemmN<<<GB, 512, 0, stream>>>(h1, W2b, b2f, h2, st + 512, N);
    // final BN2
    k_final<<<NQ, 256, 0, stream>>>(h2, st + 512, g2, bt2, outp, N);
}